// Round 1
// baseline (75.714 us; speedup 1.0000x reference)
//
#include <hip/hip_runtime.h>

#define BB 8
#define TT 2048
#define DD 128
#define CH 32              // k-chunks (64 rows each): gram grid = CH*BB = 256 blocks (full GPU)
#define GT_STRIDE 72       // bf16 elems per Gt row (64 + 8 pad)

typedef __attribute__((ext_vector_type(8))) short bf16x8;
typedef __attribute__((ext_vector_type(4))) float f32x4;
typedef unsigned short u16;

static __device__ __forceinline__ float bf2f(u16 u) {
    union { unsigned int i; float f; } v; v.i = ((unsigned int)u) << 16; return v.f;
}
static __device__ __forceinline__ u16 f2bf(float f) {
    union { float f; unsigned int i; } v; v.f = f;
    unsigned int x = v.i;
    return (u16)((x + 0x7FFFu + ((x >> 16) & 1u)) >> 16);  // RNE
}

// ===========================================================================
// Kernel 1: MFMA partial Gram. P[chunk][b] = enc_chunk^T @ enc_chunk over a
// 64-row chunk (K=64). This is exactly one tt-phase of the R9 kernel: single
// load->LDS->MFMA pipeline, no second serialized phase. 256 blocks = full GPU.
//
// P layout (frag-keyed): within each 16x16 tile, producing lane (q,ln) stores
// its 4 C-regs at elem offset ln*16 + (q>>1)*8 + (q&1)*4, so the apply
// kernel's B-fragment is ONE contiguous 16B group (single ds_read_b128).
// Element-wise reduction over chunks preserves the layout.
// ===========================================================================
__global__ __launch_bounds__(256, 1) void gram_mfma(const float* __restrict__ enc,
                                                    u16* __restrict__ P) {
    const int b     = blockIdx.y;
    const int chunk = blockIdx.x;          // 0..CH-1, 64 rows each
    const int t     = threadIdx.x;

    __shared__ __align__(16) u16 Gt[DD * GT_STRIDE];   // [d][k] = enc^T, 18 KB

    const int d  = t & 127;
    const int kh = t >> 7;                 // 0..1
    const int wave = t >> 6, lane = t & 63, quad = lane >> 4, ln = lane & 15;

    f32x4 acc[2][8];
    #pragma unroll
    for (int mi = 0; mi < 2; ++mi)
        #pragma unroll
        for (int nt = 0; nt < 8; ++nt) acc[mi][nt] = (f32x4){0.f, 0.f, 0.f, 0.f};

    const float* src = enc + ((size_t)b * TT + (size_t)chunk * 64) * DD;
    #pragma unroll
    for (int a = 0; a < 8; ++a) {
        const int k4 = a * 2 + kh;         // 0..15 -> rows k4*4+i cover 0..63
        u16 o[4];
        #pragma unroll
        for (int i = 0; i < 4; ++i)
            o[i] = f2bf(src[(k4 * 4 + i) * DD + d]);
        *(ushort4*)&Gt[d * GT_STRIDE + k4 * 4] = *(const ushort4*)o;
    }
    __syncthreads();

    bf16x8 afrag[2][2];
    #pragma unroll
    for (int mi = 0; mi < 2; ++mi)
        #pragma unroll
        for (int ks = 0; ks < 2; ++ks)
            afrag[mi][ks] = *(const bf16x8*)&Gt[((wave * 2 + mi) * 16 + ln) * GT_STRIDE
                                                + ks * 32 + quad * 8];
    #pragma unroll
    for (int ks = 0; ks < 2; ++ks) {
        #pragma unroll
        for (int nt = 0; nt < 8; ++nt) {
            const bf16x8 bfrag = *(const bf16x8*)&Gt[(nt * 16 + ln) * GT_STRIDE
                                                     + ks * 32 + quad * 8];
            #pragma unroll
            for (int mi = 0; mi < 2; ++mi)
                acc[mi][nt] = __builtin_amdgcn_mfma_f32_16x16x32_bf16(
                    afrag[mi][ks], bfrag, acc[mi][nt], 0, 0, 0);
        }
    }

    // Epilogue: b64 stores in the frag-keyed layout (512B contiguous per tile).
    u16* Pb = P + ((size_t)chunk * BB + b) * (DD * DD);
    const int off = ln * 16 + (quad >> 1) * 8 + (quad & 1) * 4;
    #pragma unroll
    for (int mi = 0; mi < 2; ++mi) {
        #pragma unroll
        for (int nt = 0; nt < 8; ++nt) {
            u16 o[4];
            #pragma unroll
            for (int r = 0; r < 4; ++r) o[r] = f2bf(acc[mi][nt][r]);
            const int tile = (wave * 2 + mi) * 8 + nt;
            *(ushort4*)&Pb[tile * 256 + off] = *(const ushort4*)o;
        }
    }
}

// ===========================================================================
// Kernel 2: element-wise reduce over chunks: Gw[b] = sum_c P[c][b]  (bf16 out).
// Layout-agnostic. 256 blocks x 128 threads = full-CU spread, 32-deep unroll
// keeps 32 x 8B loads in flight per thread (streaming, latency-covered).
// ===========================================================================
__global__ __launch_bounds__(128) void gram_reduce(const u16* __restrict__ P,
                                                   u16* __restrict__ Gw) {
    const int g = blockIdx.x * 128 + threadIdx.x;   // 0..32767
    const ushort4* Pu = (const ushort4*)P;
    const int stride = BB * DD * DD / 4;
    float sx = 0.f, sy = 0.f, sz = 0.f, sw = 0.f;
    #pragma unroll
    for (int c = 0; c < CH; ++c) {
        const ushort4 v = Pu[(size_t)c * stride + g];
        sx += bf2f(v.x); sy += bf2f(v.y); sz += bf2f(v.z); sw += bf2f(v.w);
    }
    ushort4 o; o.x = f2bf(sx); o.y = f2bf(sy); o.z = f2bf(sz); o.w = f2bf(sw);
    ((ushort4*)Gw)[g] = o;
}

// ===========================================================================
// Kernel 3: out[b] = dec[b] @ G[b] via MFMA. Grid (32 q-chunks, 8 batches).
// A-fragments (dec) loaded DIRECTLY from global (8 consecutive fp32 per lane
// per kstep = 128B contiguous per row across a wave), converted fp32->bf16 in
// registers BEFORE the Gs barrier. No Ds LDS at all. Byte-identical to R9.
// ===========================================================================
__global__ __launch_bounds__(256, 1) void apply_mfma(const float* __restrict__ dec,
                                                     const u16* __restrict__ Gw,
                                                     float* __restrict__ out) {
    const int b     = blockIdx.y;
    const int chunk = blockIdx.x;
    const int t     = threadIdx.x;

    __shared__ __align__(16) u16 Gs[DD * DD];          // 32 KB, frag-keyed layout

    const int wave = t >> 6, lane = t & 63, quad = lane >> 4, ln = lane & 15;
    const int qt = wave * 16;

    // Issue dec loads first (independent of LDS) so they overlap Gs staging.
    const float* drow = dec + ((size_t)b * TT + (size_t)chunk * 64 + qt + ln) * DD
                        + quad * 8;
    float4 dv[4][2];
    #pragma unroll
    for (int ks = 0; ks < 4; ++ks) {
        dv[ks][0] = *(const float4*)(drow + ks * 32);
        dv[ks][1] = *(const float4*)(drow + ks * 32 + 4);
    }

    // Stage G[b] raw (frag-keyed layout), coalesced uint4.
    const uint4* gsrc = (const uint4*)(Gw + (size_t)b * DD * DD);
    #pragma unroll
    for (int i = 0; i < 8; ++i)
        ((uint4*)Gs)[i * 256 + t] = gsrc[i * 256 + t];

    // Convert A-frags in registers (RNE, identical to staged values).
    bf16x8 afrag[4];
    #pragma unroll
    for (int ks = 0; ks < 4; ++ks) {
        union { u16 o[8]; bf16x8 v; } u;
        u.o[0] = f2bf(dv[ks][0].x); u.o[1] = f2bf(dv[ks][0].y);
        u.o[2] = f2bf(dv[ks][0].z); u.o[3] = f2bf(dv[ks][0].w);
        u.o[4] = f2bf(dv[ks][1].x); u.o[5] = f2bf(dv[ks][1].y);
        u.o[6] = f2bf(dv[ks][1].z); u.o[7] = f2bf(dv[ks][1].w);
        afrag[ks] = u.v;
    }
    __syncthreads();

    f32x4 acc[8];
    #pragma unroll
    for (int dt = 0; dt < 8; ++dt) acc[dt] = (f32x4){0.f, 0.f, 0.f, 0.f};

    #pragma unroll
    for (int ks = 0; ks < 4; ++ks) {
        const int mtk  = ks * 2 + (quad >> 1);
        const int boff = ln * 16 + (quad & 1) * 8;
        #pragma unroll
        for (int dt = 0; dt < 8; ++dt) {
            const bf16x8 bb = *(const bf16x8*)&Gs[(mtk * 8 + dt) * 256 + boff];
            acc[dt] = __builtin_amdgcn_mfma_f32_16x16x32_bf16(afrag[ks], bb, acc[dt], 0, 0, 0);
        }
    }

    // Epilogue: C/D layout col=lane&15, row=quad*4+reg (HW-verified R4-R8).
    float* ob = out + ((size_t)b * TT + (size_t)chunk * 64) * DD;
    #pragma unroll
    for (int dt = 0; dt < 8; ++dt) {
        const int dcol = dt * 16 + ln;
        #pragma unroll
        for (int r = 0; r < 4; ++r) {
            const int q = qt + quad * 4 + r;
            ob[q * DD + dcol] = acc[dt][r];
        }
    }
}

extern "C" void kernel_launch(void* const* d_in, const int* in_sizes, int n_in,
                              void* d_out, int out_size, void* d_ws, size_t ws_size,
                              hipStream_t stream) {
    const float* enc = (const float*)d_in[0];  // (8,2048,128) fp32
    const float* dec = (const float*)d_in[1];  // (8,2048,128) fp32
    float* out = (float*)d_out;                // (8,2048,128) fp32

    // ws: P bf16 partials (CH * 256 KB = 8 MB) | Gw bf16 (256 KB)
    u16* P  = (u16*)d_ws;
    u16* Gw = (u16*)((char*)d_ws + (size_t)CH * BB * DD * DD * sizeof(u16));

    gram_mfma<<<dim3(CH, BB), 256, 0, stream>>>(enc, P);
    gram_reduce<<<BB * DD * DD / 4 / 128, 128, 0, stream>>>(P, Gw);
    apply_mfma<<<dim3(TT / 64, BB), 256, 0, stream>>>(dec, Gw, out);
}